// Round 1
// baseline (524.814 us; speedup 1.0000x reference)
//
#include <hip/hip_runtime.h>

#define NGRAPH 4000
#define NNODE  64
#define NCH    64
#define EPG    512
#define NPAD   68   // 68 % 32 == 4 -> bank (4*i + k) % 32, worst 2-way (free)

__global__ __launch_bounds__(256) void gcn3_kernel(
    const float* __restrict__ x,
    const int*   __restrict__ ei,
    const float* __restrict__ W1, const float* __restrict__ b1,
    const float* __restrict__ W2, const float* __restrict__ b2,
    const float* __restrict__ W3, const float* __restrict__ b3,
    float* __restrict__ y, int etot)
{
    __shared__ float H [NNODE * NPAD];   // current activations
    __shared__ float Hl[NNODE * NPAD];   // linear output (h @ W)
    __shared__ int   s_esrc[EPG];
    __shared__ int   s_edst[EPG];
    __shared__ int   s_srt [EPG];        // src ids sorted by dst
    __shared__ float s_nrm [EPG];        // norm per sorted edge
    __shared__ int   s_deg [NNODE];
    __shared__ int   s_start[NNODE + 1];
    __shared__ float s_dinv[NNODE];
    __shared__ float s_red[4];

    const int g = blockIdx.x;
    const int t = threadIdx.x;

    if (t < NNODE) s_deg[t] = 0;
    __syncthreads();

    // ---- load edges (2 per thread), make node ids graph-local ----
    const int  base = g * NNODE;
    const int* srcp = ei + (size_t)g * EPG;
    const int* dstp = ei + (size_t)etot + (size_t)g * EPG;
    {
        const int e0 = t * 2;
        const int sa = srcp[e0]     - base, da = dstp[e0]     - base;
        const int sb = srcp[e0 + 1] - base, db = dstp[e0 + 1] - base;
        s_esrc[e0]     = sa; s_edst[e0]     = da;
        s_esrc[e0 + 1] = sb; s_edst[e0 + 1] = db;
        atomicAdd(&s_deg[da], 1);
        atomicAdd(&s_deg[db], 1);
    }

    // ---- load x tile (4096 contiguous floats) into padded LDS ----
    const float4* xg = reinterpret_cast<const float4*>(x + (size_t)g * (NNODE * NCH));
    #pragma unroll
    for (int it = 0; it < 4; ++it) {
        const int e4 = t + it * 256;       // float4 index 0..1023
        const float4 v = xg[e4];
        const int e = e4 * 4;
        const int i = e >> 6, k = e & 63;  // 64 divisible by 4 -> stays in row
        *reinterpret_cast<float4*>(&H[i * NPAD + k]) = v;
    }
    __syncthreads();

    // ---- dinv = 1/sqrt(deg+1)  (self-loop included in degree) ----
    if (t < NNODE) s_dinv[t] = 1.0f / sqrtf((float)(s_deg[t] + 1));
    if (t == 0) {
        int acc = 0;
        #pragma unroll 1
        for (int i = 0; i < NNODE; ++i) { s_start[i] = acc; acc += s_deg[i]; }
        s_start[NNODE] = acc;
    }
    __syncthreads();

    // ---- deterministic counting sort by dst: thread n gathers its in-edges ----
    if (t < NNODE) {
        const int n = t;
        int p = s_start[n];
        const float di = s_dinv[n];
        #pragma unroll 1
        for (int e = 0; e < EPG; ++e) {
            if (s_edst[e] == n) {
                const int s = s_esrc[e];
                s_srt[p] = s;
                s_nrm[p] = di * s_dinv[s];
                ++p;
            }
        }
    }
    __syncthreads();

    const float* Wt[3] = {W1, W2, W3};
    const float* bt[3] = {b1, b2, b3};

    const int ty = t >> 4, tx = t & 15;
    const int i0 = ty * 4, j0 = tx * 4;      // GEMM 4x4 tile
    const int n  = t >> 2, c0 = (t & 3) * 16; // aggregation: 4 threads/node

    #pragma unroll 1
    for (int layer = 0; layer < 3; ++layer) {
        const float* __restrict__ W = Wt[layer];
        const float* __restrict__ b = bt[layer];

        // ---- GEMM: Hl = H @ W  (thread computes 4x4 tile) ----
        float acc[4][4];
        #pragma unroll
        for (int r = 0; r < 4; ++r)
            #pragma unroll
            for (int c = 0; c < 4; ++c) acc[r][c] = 0.f;

        #pragma unroll 4
        for (int k = 0; k < 64; ++k) {
            const float4 w = *reinterpret_cast<const float4*>(&W[k * 64 + j0]);
            const float h0 = H[(i0 + 0) * NPAD + k];
            const float h1 = H[(i0 + 1) * NPAD + k];
            const float h2 = H[(i0 + 2) * NPAD + k];
            const float h3 = H[(i0 + 3) * NPAD + k];
            acc[0][0] += h0 * w.x; acc[0][1] += h0 * w.y; acc[0][2] += h0 * w.z; acc[0][3] += h0 * w.w;
            acc[1][0] += h1 * w.x; acc[1][1] += h1 * w.y; acc[1][2] += h1 * w.z; acc[1][3] += h1 * w.w;
            acc[2][0] += h2 * w.x; acc[2][1] += h2 * w.y; acc[2][2] += h2 * w.z; acc[2][3] += h2 * w.w;
            acc[3][0] += h3 * w.x; acc[3][1] += h3 * w.y; acc[3][2] += h3 * w.z; acc[3][3] += h3 * w.w;
        }
        #pragma unroll
        for (int r = 0; r < 4; ++r) {
            float4 o; o.x = acc[r][0]; o.y = acc[r][1]; o.z = acc[r][2]; o.w = acc[r][3];
            *reinterpret_cast<float4*>(&Hl[(i0 + r) * NPAD + j0]) = o;
        }
        __syncthreads();

        // ---- aggregate: H[n][c] = sum_e nrm*Hl[src][c] + dinv^2*Hl[n][c] + b[c] ----
        {
            const float di = s_dinv[n];
            const float sn = di * di;
            float av[16];
            #pragma unroll
            for (int q = 0; q < 4; ++q) {
                const float4 v = *reinterpret_cast<const float4*>(&Hl[n * NPAD + c0 + 4 * q]);
                av[4*q+0] = sn * v.x; av[4*q+1] = sn * v.y; av[4*q+2] = sn * v.z; av[4*q+3] = sn * v.w;
            }
            const int e_beg = s_start[n], e_end = s_start[n + 1];
            #pragma unroll 1
            for (int e = e_beg; e < e_end; ++e) {
                const int   s  = s_srt[e];
                const float nm = s_nrm[e];
                const float* hs = &Hl[s * NPAD + c0];
                #pragma unroll
                for (int q = 0; q < 4; ++q) {
                    const float4 v = *reinterpret_cast<const float4*>(&hs[4 * q]);
                    av[4*q+0] += nm * v.x; av[4*q+1] += nm * v.y;
                    av[4*q+2] += nm * v.z; av[4*q+3] += nm * v.w;
                }
            }
            __syncthreads();   // Hl reads done before next GEMM overwrites; H writes below
            #pragma unroll
            for (int q = 0; q < 4; ++q) {
                float4 o;
                o.x = av[4*q+0] + b[c0 + 4*q + 0];
                o.y = av[4*q+1] + b[c0 + 4*q + 1];
                o.z = av[4*q+2] + b[c0 + 4*q + 2];
                o.w = av[4*q+3] + b[c0 + 4*q + 3];
                *reinterpret_cast<float4*>(&H[n * NPAD + c0 + 4 * q]) = o;
            }
        }
        __syncthreads();
    }

    // ---- readout: y[g] = mean over 64x64 ----
    float ps = 0.f;
    #pragma unroll
    for (int q = 0; q < 4; ++q) {
        const float4 v = *reinterpret_cast<const float4*>(&H[n * NPAD + c0 + 4 * q]);
        ps += v.x + v.y + v.z + v.w;
    }
    #pragma unroll
    for (int off = 32; off > 0; off >>= 1)
        ps += __shfl_down(ps, off, 64);
    if ((t & 63) == 0) s_red[t >> 6] = ps;
    __syncthreads();
    if (t == 0) {
        y[g] = (s_red[0] + s_red[1] + s_red[2] + s_red[3]) * (1.0f / 4096.0f);
    }
}

extern "C" void kernel_launch(void* const* d_in, const int* in_sizes, int n_in,
                              void* d_out, int out_size, void* d_ws, size_t ws_size,
                              hipStream_t stream) {
    const float* x  = (const float*)d_in[0];
    const int*   ei = (const int*)  d_in[1];
    const float* W1 = (const float*)d_in[2];
    const float* b1 = (const float*)d_in[3];
    const float* W2 = (const float*)d_in[4];
    const float* b2 = (const float*)d_in[5];
    const float* W3 = (const float*)d_in[6];
    const float* b3 = (const float*)d_in[7];
    float* y = (float*)d_out;
    const int etot = in_sizes[1] / 2;   // 2,048,000

    hipLaunchKernelGGL(gcn3_kernel, dim3(NGRAPH), dim3(256), 0, stream,
                       x, ei, W1, b1, W2, b2, W3, b3, y, etot);
}

// Round 2
// 53.365 us; speedup vs baseline: 9.8344x; 9.8344x over previous
//
#include <hip/hip_runtime.h>

typedef _Float16 half4 __attribute__((ext_vector_type(4)));
typedef _Float16 half8 __attribute__((ext_vector_type(8)));
typedef float    f32x4 __attribute__((ext_vector_type(4)));

#define NG   4000
#define EPG  512
#define LDH  72    // padded LDS row stride in f16 elems (144 B -> 2-way bank conflicts = free)

// ---- prep: wt[layer][c][k] = W_layer[k][c] as f16 (A-operand = W^T, row-major) ----
__global__ __launch_bounds__(256) void prep_wt(const float* __restrict__ W1,
                                               const float* __restrict__ W2,
                                               const float* __restrict__ W3,
                                               _Float16* __restrict__ wt) {
    int i = blockIdx.x * 256 + threadIdx.x;
    if (i >= 3 * 4096) return;
    int layer = i >> 12, r = i & 4095;
    int c = r >> 6, k = r & 63;
    const float* W = layer == 0 ? W1 : (layer == 1 ? W2 : W3);
    wt[i] = (_Float16)W[k * 64 + c];
}

// fragment loads: lane l -> row (own-index l&15 base), k = 4*(l>>4) + {0..3} and +16
__device__ inline half8 ldsfrag(const _Float16* base, int row, int kb) {
    half4 lo = *(const half4*)(base + row * LDH + kb);
    half4 hi = *(const half4*)(base + row * LDH + kb + 16);
    return __builtin_shufflevector(lo, hi, 0, 1, 2, 3, 4, 5, 6, 7);
}
__device__ inline half8 gblfrag(const _Float16* base, int row, int kb) {
    half4 lo = *(const half4*)(base + row * 64 + kb);
    half4 hi = *(const half4*)(base + row * 64 + kb + 16);
    return __builtin_shufflevector(lo, hi, 0, 1, 2, 3, 4, 5, 6, 7);
}

// one GCN layer: HlT = (H @ W)^T via W^T @ H^T ; H' = A_hat @ Hl (+bias)
// LAST: accumulate readout partial sum instead of writing H'
template <bool LAST>
__device__ inline float layer_step(const _Float16* __restrict__ wl,
                                   const float* __restrict__ bias,
                                   _Float16* H, _Float16* HlT, const _Float16* Af,
                                   int lane, int w) {
    const int m0 = 16 * w;
    const int l15 = lane & 15, kb = 4 * (lane >> 4);
    const int rb = m0 + 4 * (lane >> 4);

    // GEMM1: D[c][s] = sum_k W^T[c][k] * H[s][k]   (A from global wt, B from LDS H)
    half8 a0 = gblfrag(wl, m0 + l15, kb);
    half8 a1 = gblfrag(wl, m0 + l15, kb + 32);
    #pragma unroll
    for (int nt = 0; nt < 4; ++nt) {
        const int n0 = 16 * nt;
        half8 b0 = ldsfrag(H, n0 + l15, kb);
        half8 b1 = ldsfrag(H, n0 + l15, kb + 32);
        f32x4 acc = {0.f, 0.f, 0.f, 0.f};
        acc = __builtin_amdgcn_mfma_f32_16x16x32_f16(a0, b0, acc, 0, 0, 0);
        acc = __builtin_amdgcn_mfma_f32_16x16x32_f16(a1, b1, acc, 0, 0, 0);
        #pragma unroll
        for (int r = 0; r < 4; ++r)
            HlT[(rb + r) * LDH + n0 + l15] = (_Float16)acc[r];   // HlT[c][s]
    }
    __syncthreads();

    // GEMM2: H'[d][c] = sum_s A_hat[d][s] * HlT[c][s]
    float ps = 0.f;
    half8 f0 = ldsfrag(Af, m0 + l15, kb);
    half8 f1 = ldsfrag(Af, m0 + l15, kb + 32);
    #pragma unroll
    for (int ct = 0; ct < 4; ++ct) {
        const int c0 = 16 * ct;
        half8 b0 = ldsfrag(HlT, c0 + l15, kb);
        half8 b1 = ldsfrag(HlT, c0 + l15, kb + 32);
        f32x4 acc = {0.f, 0.f, 0.f, 0.f};
        acc = __builtin_amdgcn_mfma_f32_16x16x32_f16(f0, b0, acc, 0, 0, 0);
        acc = __builtin_amdgcn_mfma_f32_16x16x32_f16(f1, b1, acc, 0, 0, 0);
        const float bb = bias[c0 + l15];
        if (LAST) {
            #pragma unroll
            for (int r = 0; r < 4; ++r) ps += acc[r] + bb;
        } else {
            #pragma unroll
            for (int r = 0; r < 4; ++r)
                H[(rb + r) * LDH + c0 + l15] = (_Float16)(acc[r] + bb);
        }
    }
    __syncthreads();
    return ps;
}

__global__ __launch_bounds__(256, 5) void gcn3_mfma(
    const float* __restrict__ x, const int* __restrict__ ei,
    const _Float16* __restrict__ wt,
    const float* __restrict__ b1, const float* __restrict__ b2,
    const float* __restrict__ b3,
    float* __restrict__ y, int etot)
{
    __shared__ __align__(16) char smem[28416];
    _Float16* H    = (_Float16*)(smem);            // [64][72] f16
    _Float16* HlT  = (_Float16*)(smem + 9216);     // [64][72] f16 (layers)
    _Float16* Af   = (_Float16*)(smem + 18432);    // [64][72] f16 A_hat
    int*      Aint = (int*)(smem + 9216);          // [64][64] int (setup; aliases HlT/Af head)
    int*      deg  = (int*)(smem + 27648);         // [64]
    float*    dinv = (float*)(smem + 27904);       // [64]
    float*    red  = (float*)(smem + 28160);       // [4]

    const int g = blockIdx.x, t = threadIdx.x;
    const int lane = t & 63, w = t >> 6;
    const int base = g * 64;

    // edges -> registers (2 per thread)
    const int* srcp = ei + (size_t)g * EPG;
    const int* dstp = ei + (size_t)etot + (size_t)g * EPG;
    const int2 sv = *(const int2*)(srcp + 2 * t);
    const int2 dv = *(const int2*)(dstp + 2 * t);
    const int sa = sv.x - base, da = dv.x - base;
    const int sb = sv.y - base, db = dv.y - base;

    if (t < 64) deg[t] = 0;
    {   // zero Aint (4096 ints)
        int4 z = {0, 0, 0, 0};
        int4* A4 = (int4*)Aint;
        #pragma unroll
        for (int q = 0; q < 4; ++q) A4[t + 256 * q] = z;
    }
    // x -> H (f32 global -> f16 LDS, padded rows)
    const float4* xg = (const float4*)(x + (size_t)g * 4096);
    #pragma unroll
    for (int it = 0; it < 4; ++it) {
        const int e4 = t + 256 * it;            // float4 index 0..1023
        const float4 v = xg[e4];
        const int rowx = e4 >> 4, colx = (e4 & 15) * 4;
        half4 hv = {(_Float16)v.x, (_Float16)v.y, (_Float16)v.z, (_Float16)v.w};
        *(half4*)(H + rowx * LDH + colx) = hv;
    }
    __syncthreads();

    // deterministic integer accumulation of degree and adjacency counts
    atomicAdd(&deg[da], 1);
    atomicAdd(&deg[db], 1);
    atomicAdd(&Aint[da * 64 + sa], 1);
    atomicAdd(&Aint[db * 64 + sb], 1);
    __syncthreads();
    if (t < 64) dinv[t] = rsqrtf((float)(deg[t] + 1));   // +1 = self-loop
    __syncthreads();

    // Aint -> Af (f16): reg-staged because regions alias
    {
        const int row = t >> 2, cc = (t & 3) * 16;
        int4  ci[4];
        float4 dc4[4];
        #pragma unroll
        for (int q = 0; q < 4; ++q) ci[q] = *(const int4*)(Aint + row * 64 + cc + 4 * q);
        #pragma unroll
        for (int q = 0; q < 4; ++q) dc4[q] = *(const float4*)(dinv + cc + 4 * q);
        const float dr = dinv[row];
        __syncthreads();   // all reads done before any overlapping writes
        const int*   cip = (const int*)ci;
        const float* dcp = (const float*)dc4;
        #pragma unroll
        for (int hh = 0; hh < 2; ++hh) {
            half8 hv;
            #pragma unroll
            for (int j = 0; j < 8; ++j) {
                const int idx = 8 * hh + j;
                float val = (float)cip[idx] * dr * dcp[idx];
                if (row == cc + idx) val += dr * dr;      // self-loop diag
                hv[j] = (_Float16)val;
            }
            *(half8*)(Af + row * LDH + cc + 8 * hh) = hv;
        }
    }
    __syncthreads();

    float ps = 0.f;
    layer_step<false>(wt,        b1, H, HlT, Af, lane, w);
    layer_step<false>(wt + 4096, b2, H, HlT, Af, lane, w);
    ps = layer_step<true>(wt + 8192, b3, H, HlT, Af, lane, w);

    #pragma unroll
    for (int off = 32; off > 0; off >>= 1) ps += __shfl_down(ps, off, 64);
    if (lane == 0) red[w] = ps;
    __syncthreads();
    if (t == 0) y[g] = (red[0] + red[1] + red[2] + red[3]) * (1.0f / 4096.0f);
}

extern "C" void kernel_launch(void* const* d_in, const int* in_sizes, int n_in,
                              void* d_out, int out_size, void* d_ws, size_t ws_size,
                              hipStream_t stream) {
    const float* x  = (const float*)d_in[0];
    const int*   ei = (const int*)  d_in[1];
    const float* W1 = (const float*)d_in[2];
    const float* b1 = (const float*)d_in[3];
    const float* W2 = (const float*)d_in[4];
    const float* b2 = (const float*)d_in[5];
    const float* W3 = (const float*)d_in[6];
    const float* b3 = (const float*)d_in[7];
    float* y = (float*)d_out;
    const int etot = in_sizes[1] / 2;     // 2,048,000

    _Float16* wt = (_Float16*)d_ws;       // 3*4096 f16 = 24 KB
    hipLaunchKernelGGL(prep_wt, dim3(48), dim3(256), 0, stream, W1, W2, W3, wt);
    hipLaunchKernelGGL(gcn3_mfma, dim3(NG), dim3(256), 0, stream,
                       x, ei, wt, b1, b2, b3, y, etot);
}

// Round 3
// 35.117 us; speedup vs baseline: 14.9448x; 1.5196x over previous
//
#include <hip/hip_runtime.h>

typedef _Float16 half4_t __attribute__((ext_vector_type(4)));
typedef _Float16 half8_t __attribute__((ext_vector_type(8)));
typedef float    f32x4   __attribute__((ext_vector_type(4)));

#define NG   4000
#define EPG  512
#define LDH  76   // halves; 152 B = 38 dwords == 6 mod 32 -> conflict-free b64 row-fragment reads

// ---- prep: pack W (3 x [64][64] f32, row-major k x c) into MFMA B-fragment order ----
// wb[layer][f = c0tile*2 + ktile][lane][8]  (f16)
__global__ __launch_bounds__(256) void prep_wb(const float* __restrict__ W1,
                                               const float* __restrict__ W2,
                                               const float* __restrict__ W3,
                                               _Float16* __restrict__ wb) {
    int e = blockIdx.x * 256 + threadIdx.x;     // 0..1535
    if (e >= 1536) return;
    int layer = e >> 9, rem = e & 511, f = rem >> 6, l = rem & 63;
    const float* W = layer == 0 ? W1 : (layer == 1 ? W2 : W3);
    int c  = (f >> 1) * 16 + (l & 15);
    int kb = (f & 1) * 32 + 4 * (l >> 4);
    half8_t v;
    #pragma unroll
    for (int j = 0; j < 4; ++j) v[j]     = (_Float16)W[(kb + j) * 64 + c];
    #pragma unroll
    for (int j = 0; j < 4; ++j) v[4 + j] = (_Float16)W[(kb + 16 + j) * 64 + c];
    *(half8_t*)(wb + (size_t)e * 8) = v;
}

// row-fragment load from padded row-major LDS: elems 0-3 = k kb..kb+3, elems 4-7 = kb+16..kb+19
__device__ inline half8_t ldsfrag(const _Float16* base, int row, int kb) {
    half4_t lo = *(const half4_t*)(base + row * LDH + kb);
    half4_t hi = *(const half4_t*)(base + row * LDH + kb + 16);
    return __builtin_shufflevector(lo, hi, 0, 1, 2, 3, 4, 5, 6, 7);
}

// one GCN layer, fully fused: Hl = Hin @ W (in-register) ; Hout = A_hat @ Hl + b
template <bool LAST>
__device__ inline float layer2(const _Float16* __restrict__ wbl,
                               const float* __restrict__ bias,
                               const _Float16* Hin, _Float16* Hout,
                               const _Float16* AfP, int lane, int w) {
    const int l15 = lane & 15, lg = lane >> 4;
    const int c0 = 16 * w;

    // W B-fragments for this wave's c-strip (global, L1-hot)
    half8_t wf0 = *(const half8_t*)(wbl + ((size_t)(w * 2 + 0) * 64 + lane) * 8);
    half8_t wf1 = *(const half8_t*)(wbl + ((size_t)(w * 2 + 1) * 64 + lane) * 8);
    const float bv = bias[c0 + l15];

    // GEMM1: D1[s][c0-strip], 4 s-tiles, K=64
    f32x4 acc1[4];
    #pragma unroll
    for (int st = 0; st < 4; ++st) {
        const int row = 16 * st + l15;
        half8_t a0 = ldsfrag(Hin, row, 4 * lg);        // k 0..31
        half8_t a1 = ldsfrag(Hin, row, 32 + 4 * lg);   // k 32..63
        f32x4 acc = {0.f, 0.f, 0.f, 0.f};
        acc = __builtin_amdgcn_mfma_f32_16x16x32_f16(a0, wf0, acc, 0, 0, 0);
        acc = __builtin_amdgcn_mfma_f32_16x16x32_f16(a1, wf1, acc, 0, 0, 0);
        acc1[st] = acc;
    }

    // in-register: D1 fragments -> GEMM2 B-fragments (k = s)
    half8_t bf0, bf1;
    #pragma unroll
    for (int j = 0; j < 4; ++j) {
        bf0[j]     = (_Float16)acc1[0][j];   // s = 4*lg + j
        bf0[4 + j] = (_Float16)acc1[1][j];   // s = 16 + 4*lg + j
        bf1[j]     = (_Float16)acc1[2][j];   // s = 32 + 4*lg + j
        bf1[4 + j] = (_Float16)acc1[3][j];   // s = 48 + 4*lg + j
    }

    // GEMM2: Hout[d][c0-strip] = A_hat @ Hl, 4 d-tiles
    float ps = 0.f;
    #pragma unroll
    for (int dt = 0; dt < 4; ++dt) {
        half8_t f0 = *(const half8_t*)(AfP + ((size_t)(dt * 2 + 0) * 64 + lane) * 8);
        half8_t f1 = *(const half8_t*)(AfP + ((size_t)(dt * 2 + 1) * 64 + lane) * 8);
        f32x4 acc = {0.f, 0.f, 0.f, 0.f};
        acc = __builtin_amdgcn_mfma_f32_16x16x32_f16(f0, bf0, acc, 0, 0, 0);
        acc = __builtin_amdgcn_mfma_f32_16x16x32_f16(f1, bf1, acc, 0, 0, 0);
        if (LAST) {
            #pragma unroll
            for (int r = 0; r < 4; ++r) ps += acc[r];
        } else {
            #pragma unroll
            for (int r = 0; r < 4; ++r)
                Hout[(16 * dt + 4 * lg + r) * LDH + c0 + l15] = (_Float16)(acc[r] + bv);
        }
    }
    if (LAST) ps += 16.f * bv;
    else __syncthreads();
    return ps;
}

__global__ __launch_bounds__(256, 5) void gcn3_mfma2(
    const float* __restrict__ x, const int* __restrict__ ei,
    const _Float16* __restrict__ wb,
    const float* __restrict__ b1, const float* __restrict__ b2,
    const float* __restrict__ b3,
    float* __restrict__ y, int etot)
{
    __shared__ __align__(16) char smem[28176];
    _Float16* H0  = (_Float16*)(smem);            // [64][76] f16
    _Float16* H1  = (_Float16*)(smem + 9728);     // [64][76] f16
    _Float16* AfP = (_Float16*)(smem + 19456);    // A_hat packed A-frags [8][64][8] f16
    int*      Aint = (int*)(smem + 9728);         // [64][64] int, aliases H1+AfP (setup only)
    int*      deg  = (int*)(smem + 27648);        // [64]
    float*    dinv = (float*)(smem + 27904);      // [64]
    float*    red  = (float*)(smem + 28160);      // [4]

    const int g = blockIdx.x, t = threadIdx.x;
    const int lane = t & 63, w = t >> 6;
    const int base = g * 64;

    // edges -> registers
    const int* srcp = ei + (size_t)g * EPG;
    const int* dstp = ei + (size_t)etot + (size_t)g * EPG;
    const int2 sv = *(const int2*)(srcp + 2 * t);
    const int2 dv = *(const int2*)(dstp + 2 * t);
    const int sa = sv.x - base, da = dv.x - base;
    const int sb = sv.y - base, db = dv.y - base;

    if (t < 64) deg[t] = 0;
    {   // zero Aint
        int4 z = {0, 0, 0, 0};
        int4* A4 = (int4*)Aint;
        #pragma unroll
        for (int q = 0; q < 4; ++q) A4[t + 256 * q] = z;
    }
    // x -> H0 (f32 -> f16, padded rows; conflict-free: row stride 38 dw == 6 mod 32)
    const float4* xg = (const float4*)(x + (size_t)g * 4096);
    float4 xr[4];
    #pragma unroll
    for (int it = 0; it < 4; ++it) xr[it] = xg[t + 256 * it];
    #pragma unroll
    for (int it = 0; it < 4; ++it) {
        const int e4 = t + 256 * it;
        const int row = e4 >> 4, col = (e4 & 15) * 4;
        half4_t hv = {(_Float16)xr[it].x, (_Float16)xr[it].y,
                      (_Float16)xr[it].z, (_Float16)xr[it].w};
        *(half4_t*)(H0 + row * LDH + col) = hv;
    }
    __syncthreads();

    atomicAdd(&deg[da], 1);
    atomicAdd(&deg[db], 1);
    atomicAdd(&Aint[da * 64 + sa], 1);
    atomicAdd(&Aint[db * 64 + sb], 1);
    __syncthreads();
    if (t < 64) dinv[t] = rsqrtf((float)(deg[t] + 1));   // +1 = self-loop
    __syncthreads();

    // Aint -> AfP (A-fragment packed), reg-staged across the alias
    int4  ci[2][2];
    float4 dc[2][2];
    float  drw[2];
    #pragma unroll
    for (int q = 0; q < 2; ++q) {
        const int e = t + 256 * q;
        const int f = e >> 6, l = e & 63;
        const int d  = (f >> 1) * 16 + (l & 15);
        const int kb = (f & 1) * 32 + 4 * (l >> 4);
        ci[q][0] = *(const int4*)(Aint + d * 64 + kb);
        ci[q][1] = *(const int4*)(Aint + d * 64 + kb + 16);
        dc[q][0] = *(const float4*)(dinv + kb);
        dc[q][1] = *(const float4*)(dinv + kb + 16);
        drw[q] = dinv[d];
    }
    __syncthreads();
    #pragma unroll
    for (int q = 0; q < 2; ++q) {
        const int e = t + 256 * q;
        const int f = e >> 6, l = e & 63;
        const int d  = (f >> 1) * 16 + (l & 15);
        const int kb = (f & 1) * 32 + 4 * (l >> 4);
        const int*   cp = (const int*)&ci[q][0];
        const float* dp = (const float*)&dc[q][0];
        half8_t hv;
        #pragma unroll
        for (int j = 0; j < 8; ++j) {
            const int s = kb + (j < 4 ? j : 12 + j);   // j>=4 -> kb+16+(j-4)
            float val = (float)cp[j] * drw[q] * dp[j];
            if (d == s) val += drw[q] * drw[q];        // self-loop diagonal
            hv[j] = (_Float16)val;
        }
        *(half8_t*)(AfP + (size_t)e * 8) = hv;
    }
    __syncthreads();

    float ps;
    layer2<false>(wb,        b1, H0, H1, AfP, lane, w);
    layer2<false>(wb + 4096, b2, H1, H0, AfP, lane, w);
    ps = layer2<true>(wb + 8192, b3, H0, H1, AfP, lane, w);

    #pragma unroll
    for (int off = 32; off > 0; off >>= 1) ps += __shfl_down(ps, off, 64);
    if (lane == 0) red[w] = ps;
    __syncthreads();
    if (t == 0) y[g] = (red[0] + red[1] + red[2] + red[3]) * (1.0f / 4096.0f);
}

extern "C" void kernel_launch(void* const* d_in, const int* in_sizes, int n_in,
                              void* d_out, int out_size, void* d_ws, size_t ws_size,
                              hipStream_t stream) {
    const float* x  = (const float*)d_in[0];
    const int*   ei = (const int*)  d_in[1];
    const float* W1 = (const float*)d_in[2];
    const float* b1 = (const float*)d_in[3];
    const float* W2 = (const float*)d_in[4];
    const float* b2 = (const float*)d_in[5];
    const float* W3 = (const float*)d_in[6];
    const float* b3 = (const float*)d_in[7];
    float* y = (float*)d_out;
    const int etot = in_sizes[1] / 2;     // 2,048,000

    _Float16* wbp = (_Float16*)d_ws;      // 1536*8 f16 = 24 KB
    hipLaunchKernelGGL(prep_wb, dim3(6), dim3(256), 0, stream, W1, W2, W3, wbp);
    hipLaunchKernelGGL(gcn3_mfma2, dim3(NG), dim3(256), 0, stream,
                       x, ei, wbp, b1, b2, b3, y, etot);
}